// Round 1
// baseline (691.141 us; speedup 1.0000x reference)
//
#include <hip/hip_runtime.h>

// ---------------------------------------------------------------------------
// ReconGNN: out = conv(relu(conv(x@W1^T)+b1) @ W2^T) + b2
// conv = symmetric-normalized GCN aggregation over edge_index (col-keyed CSR).
// Pipeline per call (graph-capture safe, no atomic scatter in hot loops):
//   memset deg -> detect int64/int32 edges -> histogram(col) -> scan ->
//   fill CSR srcs -> gemm1 -> conv1(+b1,relu) -> gemm2 -> conv2(+b2)
// ---------------------------------------------------------------------------

// ---- edge dtype detection: int64 edges read as int32 have all-zero odd words
__global__ void k_detect(const int* __restrict__ ed, int* __restrict__ flag, int nwords) {
  __shared__ int any;
  if (threadIdx.x == 0) any = 0;
  __syncthreads();
  #pragma unroll
  for (int u = 0; u < 8; ++u) {
    int idx = 2 * (threadIdx.x * 8 + u) + 1;   // odd words 1..4095
    if (idx < nwords && ed[idx] != 0) any = 1; // benign race
  }
  __syncthreads();
  if (threadIdx.x == 0) *flag = any ? 0 : 1;   // 1 => int64 layout
}

__global__ void k_hist(const int* __restrict__ ed, const int* __restrict__ flag,
                       int* __restrict__ deg, int E) {
  int e = blockIdx.x * 256 + threadIdx.x;
  if (e >= E) return;
  int is64 = *flag;
  int c = is64 ? ed[2 * (E + e)] : ed[E + e];
  atomicAdd(&deg[c], 1);
}

// ---- 3-kernel exclusive scan of deg -> row_ptr (chunk = 1024/block) ----
__global__ void k_scan_partial(const int* __restrict__ deg, int* __restrict__ bsum, int N) {
  __shared__ int sd[256];
  int t = threadIdx.x;
  int base = blockIdx.x * 1024 + t * 4;
  int s = 0;
  #pragma unroll
  for (int u = 0; u < 4; ++u) { int i = base + u; if (i < N) s += deg[i]; }
  sd[t] = s; __syncthreads();
  for (int off = 128; off > 0; off >>= 1) {
    if (t < off) sd[t] += sd[t + off];
    __syncthreads();
  }
  if (t == 0) bsum[blockIdx.x] = sd[0];
}

__global__ void k_scan_bsums(int* __restrict__ bsum, int* __restrict__ rowptr,
                             int NB, int N, int E) {
  __shared__ int sd[256];
  int t = threadIdx.x;
  sd[t] = (t < NB) ? bsum[t] : 0;
  __syncthreads();
  for (int off = 1; off < 256; off <<= 1) {
    int v = (t >= off) ? sd[t - off] : 0;
    __syncthreads();
    sd[t] += v;
    __syncthreads();
  }
  if (t < NB) bsum[t] = (t == 0) ? 0 : sd[t - 1];  // exclusive block offsets
  if (t == 0) rowptr[N] = E;
}

__global__ void k_scan_final(const int* __restrict__ deg, const int* __restrict__ bsum,
                             int* __restrict__ rowptr, int* __restrict__ cursor,
                             float* __restrict__ dis, int N) {
  __shared__ int sd[256];
  int t = threadIdx.x;
  int base = blockIdx.x * 1024 + t * 4;
  int loc[4]; int s = 0;
  #pragma unroll
  for (int u = 0; u < 4; ++u) { int i = base + u; loc[u] = s; if (i < N) s += deg[i]; }
  sd[t] = s; __syncthreads();
  for (int off = 1; off < 256; off <<= 1) {
    int v = (t >= off) ? sd[t - off] : 0;
    __syncthreads();
    sd[t] += v;
    __syncthreads();
  }
  int excl = (t == 0) ? 0 : sd[t - 1];
  int bb = bsum[blockIdx.x];
  #pragma unroll
  for (int u = 0; u < 4; ++u) {
    int i = base + u;
    if (i < N) {
      int v = bb + excl + loc[u];
      rowptr[i] = v;
      cursor[i] = v;
      int d = deg[i];
      dis[i] = (d > 0) ? rsqrtf((float)d) : 0.f;
    }
  }
}

__global__ void k_fill(const int* __restrict__ ed, const int* __restrict__ flag,
                       int* __restrict__ cursor, int* __restrict__ srcs, int E) {
  int e = blockIdx.x * 256 + threadIdx.x;
  if (e >= E) return;
  int is64 = *flag;
  int r = is64 ? ed[2 * e] : ed[e];
  int c = is64 ? ed[2 * (E + e)] : ed[E + e];
  int pos = atomicAdd(&cursor[c], 1);
  srcs[pos] = r;
}

// ---- GEMM: Y[N][MREAL] = X[N][KFULL] @ W[MREAL][KFULL]^T ----
// 64x64 tile, 128 threads, 8 rows x 4 cols per thread, K staged in 64-chunks.
// XOR-swizzled LDS so all inner-loop reads are b128 with <=2-way bank aliasing.
template<int KFULL, int MREAL>
__launch_bounds__(128)
__global__ void k_gemm(const float* __restrict__ X, const float* __restrict__ W,
                       float* __restrict__ Y, int N) {
  __shared__ float xs[64 * 64];
  __shared__ float wt[64 * 64];   // k-major: wt[k][c], zero-padded c>=MREAL
  const int tid = threadIdx.x;
  const int tx = tid & 15, ty = tid >> 4;   // tx: col group, ty: row base
  const int row0 = blockIdx.x * 64;
  const int c0 = tx * 4;

  float4 acc[8];
  #pragma unroll
  for (int i = 0; i < 8; ++i) acc[i] = make_float4(0.f, 0.f, 0.f, 0.f);

  for (int kt = 0; kt < KFULL / 64; ++kt) {
    if (kt) __syncthreads();
    // stage X tile (coalesced float4), swizzle k by 4*(r&7)
    #pragma unroll
    for (int it = 0; it < 8; ++it) {
      int q = tid + 128 * it;          // 0..1023 quads
      int r = q >> 4;
      int k0 = (q & 15) << 2;
      float4 v = make_float4(0.f, 0.f, 0.f, 0.f);
      int row = row0 + r;
      if (row < N) v = *(const float4*)&X[(size_t)row * KFULL + kt * 64 + k0];
      *(float4*)&xs[r * 64 + (k0 ^ (4 * (r & 7)))] = v;
    }
    // stage W transposed (k-major), swizzle c by 4*(k&15)
    #pragma unroll
    for (int it = 0; it < 32; ++it) {
      int idx = tid + 128 * it;        // 0..4095
      int c = idx >> 6;
      int k = idx & 63;
      float v = (c < MREAL) ? W[c * KFULL + kt * 64 + k] : 0.f;
      wt[k * 64 + (c ^ (4 * (k & 15)))] = v;
    }
    __syncthreads();

    #pragma unroll
    for (int kc = 0; kc < 16; ++kc) {
      int k0 = kc * 4;
      float4 xr[8];
      #pragma unroll
      for (int i = 0; i < 8; ++i)
        xr[i] = *(const float4*)&xs[(ty + 8 * i) * 64 + (k0 ^ (4 * ty))];
      float4 wr[4];
      #pragma unroll
      for (int kk = 0; kk < 4; ++kk)
        wr[kk] = *(const float4*)&wt[(k0 + kk) * 64 + (c0 ^ (4 * ((k0 + kk) & 15)))];
      #pragma unroll
      for (int i = 0; i < 8; ++i) {
        float xv0 = xr[i].x, xv1 = xr[i].y, xv2 = xr[i].z, xv3 = xr[i].w;
        acc[i].x = fmaf(xv0, wr[0].x, acc[i].x);
        acc[i].y = fmaf(xv0, wr[0].y, acc[i].y);
        acc[i].z = fmaf(xv0, wr[0].z, acc[i].z);
        acc[i].w = fmaf(xv0, wr[0].w, acc[i].w);
        acc[i].x = fmaf(xv1, wr[1].x, acc[i].x);
        acc[i].y = fmaf(xv1, wr[1].y, acc[i].y);
        acc[i].z = fmaf(xv1, wr[1].z, acc[i].z);
        acc[i].w = fmaf(xv1, wr[1].w, acc[i].w);
        acc[i].x = fmaf(xv2, wr[2].x, acc[i].x);
        acc[i].y = fmaf(xv2, wr[2].y, acc[i].y);
        acc[i].z = fmaf(xv2, wr[2].z, acc[i].z);
        acc[i].w = fmaf(xv2, wr[2].w, acc[i].w);
        acc[i].x = fmaf(xv3, wr[3].x, acc[i].x);
        acc[i].y = fmaf(xv3, wr[3].y, acc[i].y);
        acc[i].z = fmaf(xv3, wr[3].z, acc[i].z);
        acc[i].w = fmaf(xv3, wr[3].w, acc[i].w);
      }
    }
  }

  if (c0 < MREAL) {
    #pragma unroll
    for (int i = 0; i < 8; ++i) {
      int row = row0 + ty + 8 * i;
      if (row < N) *(float4*)&Y[(size_t)row * MREAL + c0] = acc[i];
    }
  }
}

// ---- GCN conv (gather form): out[i] = act( dis[i]*sum_p H[src]*dis[src] + bias )
// one wave per node, lane = feature; srcs/dis loads are wave-broadcast.
template<int D, bool RELU>
__launch_bounds__(256)
__global__ void k_conv(const float* __restrict__ H, const int* __restrict__ rowptr,
                       const int* __restrict__ srcs, const float* __restrict__ dis,
                       const float* __restrict__ bias, float* __restrict__ out, int N) {
  int node = blockIdx.x * 4 + (threadIdx.x >> 6);
  int lane = threadIdx.x & 63;
  if (node >= N) return;
  int s = rowptr[node], e = rowptr[node + 1];
  float acc = 0.f;
  int p = s;
  for (; p + 2 <= e; p += 2) {   // 2-edge unroll for load ILP
    int s0 = srcs[p], s1 = srcs[p + 1];
    float w0 = dis[s0], w1 = dis[s1];
    float h0 = 0.f, h1 = 0.f;
    if (D == 64 || lane < D) {
      h0 = H[(size_t)s0 * D + lane];
      h1 = H[(size_t)s1 * D + lane];
    }
    acc = fmaf(h0, w0, acc);
    acc = fmaf(h1, w1, acc);
  }
  if (p < e) {
    int s0 = srcs[p];
    float w0 = dis[s0];
    float h0 = (D == 64 || lane < D) ? H[(size_t)s0 * D + lane] : 0.f;
    acc = fmaf(h0, w0, acc);
  }
  if (lane < D) {
    float v = fmaf(acc, dis[node], bias[lane]);
    out[(size_t)node * D + lane] = RELU ? fmaxf(v, 0.f) : v;
  }
}

extern "C" void kernel_launch(void* const* d_in, const int* in_sizes, int n_in,
                              void* d_out, int out_size, void* d_ws, size_t ws_size,
                              hipStream_t stream) {
  const float* x  = (const float*)d_in[0];
  const int*   ed = (const int*)d_in[1];
  const float* W1 = (const float*)d_in[2];
  const float* b1 = (const float*)d_in[3];
  const float* W2 = (const float*)d_in[4];
  const float* b2 = (const float*)d_in[5];
  float* out = (float*)d_out;

  const int FIN = 128, FH = 64, FO = 40;
  const int N = in_sizes[0] / FIN;
  const int E = in_sizes[1] / 2;

  char* ws = (char*)d_ws;
  size_t off = 0;
  auto alloc = [&](size_t bytes) {
    void* p = ws + off;
    off = (off + bytes + 255) & ~(size_t)255;
    return p;
  };
  int*   flag   = (int*)alloc(4);
  int*   deg    = (int*)alloc((size_t)N * 4);
  int*   rowptr = (int*)alloc(((size_t)N + 1) * 4);
  int*   cursor = (int*)alloc((size_t)N * 4);
  int*   bsum   = (int*)alloc(1024);
  float* dis    = (float*)alloc((size_t)N * 4);
  int*   srcs   = (int*)alloc((size_t)E * 4);
  float* h1     = (float*)alloc((size_t)N * FH * 4);
  float* h1b    = (float*)alloc((size_t)N * FH * 4);
  float* h2     = h1;   // h1 dead after conv1 -> reuse for gemm2 output [N][40]

  hipMemsetAsync(deg, 0, (size_t)N * 4, stream);
  k_detect<<<1, 256, 0, stream>>>(ed, flag, in_sizes[1]);

  int eb = (E + 255) / 256;
  int NB = (N + 1023) / 1024;           // 98 <= 256 (scan_bsums capacity)
  k_hist<<<eb, 256, 0, stream>>>(ed, flag, deg, E);
  k_scan_partial<<<NB, 256, 0, stream>>>(deg, bsum, N);
  k_scan_bsums<<<1, 256, 0, stream>>>(bsum, rowptr, NB, N, E);
  k_scan_final<<<NB, 256, 0, stream>>>(deg, bsum, rowptr, cursor, dis, N);
  k_fill<<<eb, 256, 0, stream>>>(ed, flag, cursor, srcs, E);

  int gb = (N + 63) / 64;
  int cb = (N + 3) / 4;
  k_gemm<128, 64><<<gb, 128, 0, stream>>>(x, W1, h1, N);
  k_conv<64, true><<<cb, 256, 0, stream>>>(h1, rowptr, srcs, dis, b1, h1b, N);
  k_gemm<64, 40><<<gb, 128, 0, stream>>>(h1b, W2, h2, N);
  k_conv<40, false><<<cb, 256, 0, stream>>>(h2, rowptr, srcs, dis, b2, out, N);
}

// Round 2
// 554.377 us; speedup vs baseline: 1.2467x; 1.2467x over previous
//
#include <hip/hip_runtime.h>

// ---------------------------------------------------------------------------
// ReconGNN: out = conv(relu(conv(x@W1^T)+b1) @ W2^T) + b2
// conv = symmetric-normalized GCN aggregation over edge_index (col-keyed CSR).
// Pipeline per call (graph-capture safe, no atomic scatter in hot loops):
//   memset deg -> detect int64/int32 edges -> histogram(col) -> scan ->
//   fill CSR srcs -> gemm1 -> conv1(+b1,relu) -> gemm2 -> conv2(+b2)
// R2: gemm rewritten — R1 spilled (VGPR 256, 205MB scratch writes) because
// the fully-unrolled kt+kc loops fused. New gemm: BK=32 chunks with
// `#pragma unroll 1`, 128x64 tile / 128 thr / 8x8 per thread (1 B LDS per
// FMA), XOR-swizzled X tile (conflict-free xr reads), JIT wr loads.
// ---------------------------------------------------------------------------

// ---- edge dtype detection: int64 edges read as int32 have all-zero odd words
__global__ void k_detect(const int* __restrict__ ed, int* __restrict__ flag, int nwords) {
  __shared__ int any;
  if (threadIdx.x == 0) any = 0;
  __syncthreads();
  #pragma unroll
  for (int u = 0; u < 8; ++u) {
    int idx = 2 * (threadIdx.x * 8 + u) + 1;   // odd words 1..4095
    if (idx < nwords && ed[idx] != 0) any = 1; // benign race
  }
  __syncthreads();
  if (threadIdx.x == 0) *flag = any ? 0 : 1;   // 1 => int64 layout
}

__global__ void k_hist(const int* __restrict__ ed, const int* __restrict__ flag,
                       int* __restrict__ deg, int E) {
  int e = blockIdx.x * 256 + threadIdx.x;
  if (e >= E) return;
  int is64 = *flag;
  int c = is64 ? ed[2 * (E + e)] : ed[E + e];
  atomicAdd(&deg[c], 1);
}

// ---- 3-kernel exclusive scan of deg -> row_ptr (chunk = 1024/block) ----
__global__ void k_scan_partial(const int* __restrict__ deg, int* __restrict__ bsum, int N) {
  __shared__ int sd[256];
  int t = threadIdx.x;
  int base = blockIdx.x * 1024 + t * 4;
  int s = 0;
  #pragma unroll
  for (int u = 0; u < 4; ++u) { int i = base + u; if (i < N) s += deg[i]; }
  sd[t] = s; __syncthreads();
  for (int off = 128; off > 0; off >>= 1) {
    if (t < off) sd[t] += sd[t + off];
    __syncthreads();
  }
  if (t == 0) bsum[blockIdx.x] = sd[0];
}

__global__ void k_scan_bsums(int* __restrict__ bsum, int* __restrict__ rowptr,
                             int NB, int N, int E) {
  __shared__ int sd[256];
  int t = threadIdx.x;
  sd[t] = (t < NB) ? bsum[t] : 0;
  __syncthreads();
  for (int off = 1; off < 256; off <<= 1) {
    int v = (t >= off) ? sd[t - off] : 0;
    __syncthreads();
    sd[t] += v;
    __syncthreads();
  }
  if (t < NB) bsum[t] = (t == 0) ? 0 : sd[t - 1];  // exclusive block offsets
  if (t == 0) rowptr[N] = E;
}

__global__ void k_scan_final(const int* __restrict__ deg, const int* __restrict__ bsum,
                             int* __restrict__ rowptr, int* __restrict__ cursor,
                             float* __restrict__ dis, int N) {
  __shared__ int sd[256];
  int t = threadIdx.x;
  int base = blockIdx.x * 1024 + t * 4;
  int loc[4]; int s = 0;
  #pragma unroll
  for (int u = 0; u < 4; ++u) { int i = base + u; loc[u] = s; if (i < N) s += deg[i]; }
  sd[t] = s; __syncthreads();
  for (int off = 1; off < 256; off <<= 1) {
    int v = (t >= off) ? sd[t - off] : 0;
    __syncthreads();
    sd[t] += v;
    __syncthreads();
  }
  int excl = (t == 0) ? 0 : sd[t - 1];
  int bb = bsum[blockIdx.x];
  #pragma unroll
  for (int u = 0; u < 4; ++u) {
    int i = base + u;
    if (i < N) {
      int v = bb + excl + loc[u];
      rowptr[i] = v;
      cursor[i] = v;
      int d = deg[i];
      dis[i] = (d > 0) ? rsqrtf((float)d) : 0.f;
    }
  }
}

__global__ void k_fill(const int* __restrict__ ed, const int* __restrict__ flag,
                       int* __restrict__ cursor, int* __restrict__ srcs, int E) {
  int e = blockIdx.x * 256 + threadIdx.x;
  if (e >= E) return;
  int is64 = *flag;
  int r = is64 ? ed[2 * e] : ed[e];
  int c = is64 ? ed[2 * (E + e)] : ed[E + e];
  int pos = atomicAdd(&cursor[c], 1);
  srcs[pos] = r;
}

// ---- GEMM: Y[N][MREAL] = X[N][KFULL] @ W[MREAL][KFULL]^T ----
// BM=128 x BN=64 tile, 128 threads, 8x8 outputs per thread, BK=32 chunks.
// X tile k-quad XOR-swizzled so compute reads are conflict-free b128.
template<int KFULL, int MREAL>
__launch_bounds__(128)
__global__ void k_gemm(const float* __restrict__ X, const float* __restrict__ W,
                       float* __restrict__ Y, int N) {
  constexpr int BM = 128, BK = 32;
  __shared__ float xs[BM * BK];        // xs[r*32 + (kq ^ ((r>>3)&7))*4 + kl]
  __shared__ float wt[BK * 64];        // wt[k*64 + c], zero-padded c>=MREAL
  const int tid = threadIdx.x;
  const int tr = tid >> 3;             // row group 0..15  (rows tr*8 .. +7)
  const int tc = tid & 7;              // col group 0..7   (cols tc*8 .. +7)
  const int row0 = blockIdx.x * BM;
  const int c0 = tc * 8;

  float4 acc[8][2];
  #pragma unroll
  for (int i = 0; i < 8; ++i) {
    acc[i][0] = make_float4(0.f, 0.f, 0.f, 0.f);
    acc[i][1] = make_float4(0.f, 0.f, 0.f, 0.f);
  }

  #pragma unroll 1
  for (int kt = 0; kt < KFULL / BK; ++kt) {
    if (kt) __syncthreads();
    // stage X: 1024 quads, 8 per thread; wave writes spread over all banks
    #pragma unroll
    for (int j = 0; j < 8; ++j) {
      int q = tid + 128 * j;
      int r = q >> 3, kq = q & 7;
      float4 v = make_float4(0.f, 0.f, 0.f, 0.f);
      int row = row0 + r;
      if (row < N) v = *(const float4*)&X[(size_t)row * KFULL + kt * BK + kq * 4];
      *(float4*)&xs[r * 32 + ((kq ^ ((r >> 3) & 7)) << 2)] = v;
    }
    // stage W transposed: 512 quads, 4 per thread, scalar LDS stores
    #pragma unroll
    for (int j = 0; j < 4; ++j) {
      int q = tid + 128 * j;
      int c = q >> 3, kq = q & 7;
      float4 v = make_float4(0.f, 0.f, 0.f, 0.f);
      if (c < MREAL) v = *(const float4*)&W[(size_t)c * KFULL + kt * BK + kq * 4];
      wt[(kq * 4 + 0) * 64 + c] = v.x;
      wt[(kq * 4 + 1) * 64 + c] = v.y;
      wt[(kq * 4 + 2) * 64 + c] = v.z;
      wt[(kq * 4 + 3) * 64 + c] = v.w;
    }
    __syncthreads();

    #pragma unroll 2
    for (int kq = 0; kq < 8; ++kq) {     // 4 k per group
      float4 xr[8];
      #pragma unroll
      for (int i = 0; i < 8; ++i)
        xr[i] = *(const float4*)&xs[(tr * 8 + i) * 32 + ((kq ^ (tr & 7)) << 2)];
      #pragma unroll
      for (int kk = 0; kk < 4; ++kk) {
        int k = kq * 4 + kk;
        float4 w0 = *(const float4*)&wt[k * 64 + c0];
        float4 w1 = *(const float4*)&wt[k * 64 + c0 + 4];
        #pragma unroll
        for (int i = 0; i < 8; ++i) {
          float xv = ((const float*)&xr[i])[kk];
          acc[i][0].x = fmaf(xv, w0.x, acc[i][0].x);
          acc[i][0].y = fmaf(xv, w0.y, acc[i][0].y);
          acc[i][0].z = fmaf(xv, w0.z, acc[i][0].z);
          acc[i][0].w = fmaf(xv, w0.w, acc[i][0].w);
          acc[i][1].x = fmaf(xv, w1.x, acc[i][1].x);
          acc[i][1].y = fmaf(xv, w1.y, acc[i][1].y);
          acc[i][1].z = fmaf(xv, w1.z, acc[i][1].z);
          acc[i][1].w = fmaf(xv, w1.w, acc[i][1].w);
        }
      }
    }
  }

  // store: per row, wave covers 256B contiguous (8 tc x 2 float4)
  #pragma unroll
  for (int i = 0; i < 8; ++i) {
    int row = row0 + tr * 8 + i;
    if (row >= N) continue;
    if (MREAL >= 64 || c0 + 3 < MREAL)
      *(float4*)&Y[(size_t)row * MREAL + c0] = acc[i][0];
    if (MREAL >= 64 || c0 + 7 < MREAL)
      *(float4*)&Y[(size_t)row * MREAL + c0 + 4] = acc[i][1];
  }
}

// ---- GCN conv (gather form): out[i] = act( dis[i]*sum_p H[src]*dis[src] + bias )
// one wave per node, lane = feature; srcs/dis loads are wave-broadcast.
template<int D, bool RELU>
__launch_bounds__(256)
__global__ void k_conv(const float* __restrict__ H, const int* __restrict__ rowptr,
                       const int* __restrict__ srcs, const float* __restrict__ dis,
                       const float* __restrict__ bias, float* __restrict__ out, int N) {
  int node = blockIdx.x * 4 + (threadIdx.x >> 6);
  int lane = threadIdx.x & 63;
  if (node >= N) return;
  int s = rowptr[node], e = rowptr[node + 1];
  float acc = 0.f;
  int p = s;
  for (; p + 2 <= e; p += 2) {   // 2-edge unroll for load ILP
    int s0 = srcs[p], s1 = srcs[p + 1];
    float w0 = dis[s0], w1 = dis[s1];
    float h0 = 0.f, h1 = 0.f;
    if (D == 64 || lane < D) {
      h0 = H[(size_t)s0 * D + lane];
      h1 = H[(size_t)s1 * D + lane];
    }
    acc = fmaf(h0, w0, acc);
    acc = fmaf(h1, w1, acc);
  }
  if (p < e) {
    int s0 = srcs[p];
    float w0 = dis[s0];
    float h0 = (D == 64 || lane < D) ? H[(size_t)s0 * D + lane] : 0.f;
    acc = fmaf(h0, w0, acc);
  }
  if (lane < D) {
    float v = fmaf(acc, dis[node], bias[lane]);
    out[(size_t)node * D + lane] = RELU ? fmaxf(v, 0.f) : v;
  }
}

extern "C" void kernel_launch(void* const* d_in, const int* in_sizes, int n_in,
                              void* d_out, int out_size, void* d_ws, size_t ws_size,
                              hipStream_t stream) {
  const float* x  = (const float*)d_in[0];
  const int*   ed = (const int*)d_in[1];
  const float* W1 = (const float*)d_in[2];
  const float* b1 = (const float*)d_in[3];
  const float* W2 = (const float*)d_in[4];
  const float* b2 = (const float*)d_in[5];
  float* out = (float*)d_out;

  const int FIN = 128, FH = 64, FO = 40;
  const int N = in_sizes[0] / FIN;
  const int E = in_sizes[1] / 2;

  char* ws = (char*)d_ws;
  size_t off = 0;
  auto alloc = [&](size_t bytes) {
    void* p = ws + off;
    off = (off + bytes + 255) & ~(size_t)255;
    return p;
  };
  int*   flag   = (int*)alloc(4);
  int*   deg    = (int*)alloc((size_t)N * 4);
  int*   rowptr = (int*)alloc(((size_t)N + 1) * 4);
  int*   cursor = (int*)alloc((size_t)N * 4);
  int*   bsum   = (int*)alloc(1024);
  float* dis    = (float*)alloc((size_t)N * 4);
  int*   srcs   = (int*)alloc((size_t)E * 4);
  float* h1     = (float*)alloc((size_t)N * FH * 4);
  float* h1b    = (float*)alloc((size_t)N * FH * 4);
  float* h2     = h1;   // h1 dead after conv1 -> reuse for gemm2 output [N][40]

  hipMemsetAsync(deg, 0, (size_t)N * 4, stream);
  k_detect<<<1, 256, 0, stream>>>(ed, flag, in_sizes[1]);

  int eb = (E + 255) / 256;
  int NB = (N + 1023) / 1024;           // 98 <= 256 (scan_bsums capacity)
  k_hist<<<eb, 256, 0, stream>>>(ed, flag, deg, E);
  k_scan_partial<<<NB, 256, 0, stream>>>(deg, bsum, N);
  k_scan_bsums<<<1, 256, 0, stream>>>(bsum, rowptr, NB, N, E);
  k_scan_final<<<NB, 256, 0, stream>>>(deg, bsum, rowptr, cursor, dis, N);
  k_fill<<<eb, 256, 0, stream>>>(ed, flag, cursor, srcs, E);

  int gb = (N + 127) / 128;
  int cb = (N + 3) / 4;
  k_gemm<128, 64><<<gb, 128, 0, stream>>>(x, W1, h1, N);
  k_conv<64, true><<<cb, 256, 0, stream>>>(h1, rowptr, srcs, dis, b1, h1b, N);
  k_gemm<64, 40><<<gb, 128, 0, stream>>>(h1b, W2, h2, N);
  k_conv<40, false><<<cb, 256, 0, stream>>>(h2, rowptr, srcs, dis, b2, out, N);
}